// Round 3
// baseline (121.230 us; speedup 1.0000x reference)
//
#include <hip/hip_runtime.h>
#include <hip/hip_bf16.h>

#define NPTS 1024
#define DIMD 64
#define KNN  16
#define HID  256   // DIM * EXP
#define EMBH 64

// ---------------- Kernel 1: q,k,v = x @ Wq/Wk/Wv (fp32) ----------------
__global__ __launch_bounds__(256) void qkv_kernel(
    const float* __restrict__ x,
    const float* __restrict__ Wq, const float* __restrict__ Wk, const float* __restrict__ Wv,
    float* __restrict__ q, float* __restrict__ k, float* __restrict__ v)
{
    int t = blockIdx.x * 256 + threadIdx.x;   // 0 .. NPTS*DIMD-1
    int i = t >> 6, d = t & 63;
    const float4* xr = (const float4*)(x + i * DIMD);
    float aq = 0.f, ak = 0.f, av = 0.f;
    #pragma unroll
    for (int cb = 0; cb < DIMD / 4; cb++) {
        float4 xv = xr[cb];
        const float* wq = Wq + (cb*4) * DIMD + d;
        const float* wk = Wk + (cb*4) * DIMD + d;
        const float* wv = Wv + (cb*4) * DIMD + d;
        aq = fmaf(xv.x, wq[0*DIMD], aq); aq = fmaf(xv.y, wq[1*DIMD], aq);
        aq = fmaf(xv.z, wq[2*DIMD], aq); aq = fmaf(xv.w, wq[3*DIMD], aq);
        ak = fmaf(xv.x, wk[0*DIMD], ak); ak = fmaf(xv.y, wk[1*DIMD], ak);
        ak = fmaf(xv.z, wk[2*DIMD], ak); ak = fmaf(xv.w, wk[3*DIMD], ak);
        av = fmaf(xv.x, wv[0*DIMD], av); av = fmaf(xv.y, wv[1*DIMD], av);
        av = fmaf(xv.z, wv[2*DIMD], av); av = fmaf(xv.w, wv[3*DIMD], av);
    }
    q[t] = aq; k[t] = ak; v[t] = av;
}

// ---------------- Kernel 2: kNN (16 smallest euclidean distances, incl. self) -----
// One wave (64 threads) per query point; 16 dists/lane in registers.
// Non-fused fp32 ops to match numpy's sqrt((dx^2+dy^2)+dz^2) compare key exactly.
__global__ __launch_bounds__(64) void knn_kernel(
    const float* __restrict__ pos, int* __restrict__ idx)
{
    int i = blockIdx.x;
    int lane = threadIdx.x;   // 0..63
    float px = pos[i*3+0], py = pos[i*3+1], pz = pos[i*3+2];

    float dist[16];
    #pragma unroll
    for (int r = 0; r < 16; r++) {
        int j = lane + 64 * r;
        float dx = __fsub_rn(px, pos[j*3+0]);
        float dy = __fsub_rn(py, pos[j*3+1]);
        float dz = __fsub_rn(pz, pos[j*3+2]);
        float s  = __fadd_rn(__fadd_rn(__fmul_rn(dx,dx), __fmul_rn(dy,dy)), __fmul_rn(dz,dz));
        dist[r] = __fsqrt_rn(s);
    }

    for (int sel = 0; sel < KNN; sel++) {
        // lane-local argmin (earlier r == smaller j wins ties)
        float mv = dist[0]; int mr = 0;
        #pragma unroll
        for (int r = 1; r < 16; r++) {
            if (dist[r] < mv) { mv = dist[r]; mr = r; }
        }
        int mj = lane + 64 * mr;
        // wave butterfly argmin, tie -> smaller index (matches stable top_k)
        #pragma unroll
        for (int off = 32; off > 0; off >>= 1) {
            float ov = __shfl_xor(mv, off);
            int   oj = __shfl_xor(mj, off);
            if (ov < mv || (ov == mv && oj < mj)) { mv = ov; mj = oj; }
        }
        if (lane == 0) idx[i * KNN + sel] = mj;
        // invalidate the winner (exactly one lane owns it)
        #pragma unroll
        for (int r = 0; r < 16; r++) {
            if (lane + 64 * r == mj) dist[r] = 3.0e38f;
        }
    }
}

// ---------------- Kernel 3: fused per-point transformer layer ---------------------
__global__ __launch_bounds__(256) void ptl_main(
    const float* __restrict__ pos,
    const float* __restrict__ q, const float* __restrict__ k, const float* __restrict__ v,
    const int* __restrict__ idx,
    const float* __restrict__ P1, const float* __restrict__ pb1,
    const float* __restrict__ P2, const float* __restrict__ pb2,
    const float* __restrict__ A1, const float* __restrict__ ab1,
    const float* __restrict__ A2, const float* __restrict__ ab2,
    float* __restrict__ out)
{
    __shared__ __align__(16) float s_q[DIMD];
    __shared__ int   s_idx[KNN];
    __shared__ __align__(16) float s_emb1[KNN][EMBH];
    __shared__ __align__(16) float s_h[KNN][DIMD];
    __shared__ __align__(16) float s_vg[KNN][DIMD];
    __shared__ __align__(16) float s_hidden[KNN][HID];
    __shared__ __align__(16) float s_sim[KNN][DIMD];

    const int i = blockIdx.x;
    const int tid = threadIdx.x;

    if (tid < KNN)  s_idx[tid] = idx[i * KNN + tid];
    if (tid < DIMD) s_q[tid]   = q[i * DIMD + tid];
    __syncthreads();

    const float px = pos[i*3+0], py = pos[i*3+1], pz = pos[i*3+2];

    // Step A: emb1 = relu(rel_pos @ P1 + pb1)   [16 x 64]
    for (int t = tid; t < KNN * EMBH; t += 256) {
        int kk = t >> 6, m = t & 63;
        int j = s_idx[kk];
        float dx = px - pos[j*3+0];
        float dy = py - pos[j*3+1];
        float dz = pz - pos[j*3+2];
        float a = pb1[m];
        a = fmaf(dx, P1[0*EMBH+m], a);
        a = fmaf(dy, P1[1*EMBH+m], a);
        a = fmaf(dz, P1[2*EMBH+m], a);
        s_emb1[kk][m] = fmaxf(a, 0.0f);
    }
    __syncthreads();

    // Step B: rpe = emb1 @ P2 + pb2; h = q - k[j] + rpe; vg = v[j] + rpe   [16 x 64]
    for (int t = tid; t < KNN * DIMD; t += 256) {
        int kk = t >> 6, d = t & 63;
        int j = s_idx[kk];
        float a = pb2[d];
        const float4* e4 = (const float4*)(&s_emb1[kk][0]);
        #pragma unroll
        for (int mb = 0; mb < EMBH / 4; mb++) {
            float4 e = e4[mb];
            a = fmaf(e.x, P2[(mb*4+0)*DIMD + d], a);
            a = fmaf(e.y, P2[(mb*4+1)*DIMD + d], a);
            a = fmaf(e.z, P2[(mb*4+2)*DIMD + d], a);
            a = fmaf(e.w, P2[(mb*4+3)*DIMD + d], a);
        }
        s_h[kk][d]  = s_q[d] - k[j*DIMD + d] + a;
        s_vg[kk][d] = v[j*DIMD + d] + a;
    }
    __syncthreads();

    // Step C: hidden = relu(h @ A1 + ab1)   [16 x 256], thread owns column m = tid
    {
        float acc[KNN];
        float bias = ab1[tid];
        #pragma unroll
        for (int s = 0; s < KNN; s++) acc[s] = bias;
        #pragma unroll
        for (int cb = 0; cb < DIMD / 4; cb++) {
            float a1c[4];
            #pragma unroll
            for (int cc = 0; cc < 4; cc++) a1c[cc] = A1[(cb*4+cc) * HID + tid];
            #pragma unroll
            for (int s = 0; s < KNN; s++) {
                float4 h4 = ((const float4*)(&s_h[s][0]))[cb];   // broadcast read
                acc[s] = fmaf(h4.x, a1c[0], acc[s]);
                acc[s] = fmaf(h4.y, a1c[1], acc[s]);
                acc[s] = fmaf(h4.z, a1c[2], acc[s]);
                acc[s] = fmaf(h4.w, a1c[3], acc[s]);
            }
        }
        #pragma unroll
        for (int s = 0; s < KNN; s++) s_hidden[s][tid] = fmaxf(acc[s], 0.0f);
    }
    __syncthreads();

    // Step D: sim = hidden @ A2 + ab2   [16 x 64]; thread: d = tid&63, rows kk0+4u
    {
        int d = tid & 63;
        int kk0 = tid >> 6;
        float acc[4];
        float bias = ab2[d];
        #pragma unroll
        for (int u = 0; u < 4; u++) acc[u] = bias;
        #pragma unroll
        for (int mb = 0; mb < HID / 4; mb++) {
            float a2c[4];
            #pragma unroll
            for (int mm = 0; mm < 4; mm++) a2c[mm] = A2[(mb*4+mm) * DIMD + d];
            #pragma unroll
            for (int u = 0; u < 4; u++) {
                float4 h4 = ((const float4*)(&s_hidden[kk0 + 4*u][0]))[mb];  // broadcast
                acc[u] = fmaf(h4.x, a2c[0], acc[u]);
                acc[u] = fmaf(h4.y, a2c[1], acc[u]);
                acc[u] = fmaf(h4.z, a2c[2], acc[u]);
                acc[u] = fmaf(h4.w, a2c[3], acc[u]);
            }
        }
        #pragma unroll
        for (int u = 0; u < 4; u++) s_sim[kk0 + 4*u][d] = acc[u];
    }
    __syncthreads();

    // Step E: softmax over neighbors per output dim, then weighted sum of vg
    if (tid < DIMD) {
        int d = tid;
        float mx = -3.0e38f;
        #pragma unroll
        for (int kk = 0; kk < KNN; kk++) mx = fmaxf(mx, s_sim[kk][d]);
        float den = 0.0f, num = 0.0f;
        #pragma unroll
        for (int kk = 0; kk < KNN; kk++) {
            float e = expf(s_sim[kk][d] - mx);
            den += e;
            num = fmaf(e, s_vg[kk][d], num);
        }
        out[i * DIMD + d] = num / den;
    }
}

extern "C" void kernel_launch(void* const* d_in, const int* in_sizes, int n_in,
                              void* d_out, int out_size, void* d_ws, size_t ws_size,
                              hipStream_t stream) {
    const float* x   = (const float*)d_in[0];
    const float* pos = (const float*)d_in[1];
    const float* Wq  = (const float*)d_in[2];
    const float* Wk  = (const float*)d_in[3];
    const float* Wv  = (const float*)d_in[4];
    const float* P1  = (const float*)d_in[5];
    const float* pb1 = (const float*)d_in[6];
    const float* P2  = (const float*)d_in[7];
    const float* pb2 = (const float*)d_in[8];
    const float* A1  = (const float*)d_in[9];
    const float* ab1 = (const float*)d_in[10];
    const float* A2  = (const float*)d_in[11];
    const float* ab2 = (const float*)d_in[12];
    float* out = (float*)d_out;

    float* q  = (float*)d_ws;
    float* k  = q + NPTS * DIMD;
    float* v  = k + NPTS * DIMD;
    int* idx  = (int*)(v + NPTS * DIMD);

    qkv_kernel<<<NPTS * DIMD / 256, 256, 0, stream>>>(x, Wq, Wk, Wv, q, k, v);
    knn_kernel<<<NPTS, 64, 0, stream>>>(pos, idx);
    ptl_main<<<NPTS, 256, 0, stream>>>(pos, q, k, v, idx,
                                       P1, pb1, P2, pb2, A1, ab1, A2, ab2, out);
}

// Round 4
// 118.959 us; speedup vs baseline: 1.0191x; 1.0191x over previous
//
#include <hip/hip_runtime.h>

#define NPTS 1024
#define DIMD 64
#define KNN  16
#define HID  256   // DIM * EXP
#define EMBH 64

// One block (256 threads) per query point. Fuses qkv + knn + the whole layer.
// LDS aliasing: smem16 holds dist[1024] (phases 1-2) then hidden[16][256] (C/D).
//               s_embsim holds emb1 (A/B) then sim (D/E).
__global__ __launch_bounds__(256) void ptl_fused(
    const float* __restrict__ x,  const float* __restrict__ pos,
    const float* __restrict__ Wq, const float* __restrict__ Wk, const float* __restrict__ Wv,
    const float* __restrict__ P1, const float* __restrict__ pb1,
    const float* __restrict__ P2, const float* __restrict__ pb2,
    const float* __restrict__ A1, const float* __restrict__ ab1,
    const float* __restrict__ A2, const float* __restrict__ ab2,
    float* __restrict__ out)
{
    __shared__ __align__(16) float smem16[KNN * HID];      // 16 KB: dist[1024] | hidden
    __shared__ __align__(16) float s_embsim[KNN][EMBH];    // 4 KB: emb1 | sim
    __shared__ __align__(16) float s_xn[KNN][DIMD];        // 4 KB: neighbor x rows
    __shared__ __align__(16) float s_h[KNN][DIMD];         // 4 KB
    __shared__ __align__(16) float s_vg[KNN][DIMD];        // 4 KB
    __shared__ __align__(16) float s_q[DIMD];
    __shared__ int s_idx[KNN];

    float* s_dist = smem16;
    float (*s_hidden)[HID] = (float(*)[HID])smem16;

    const int i   = blockIdx.x;
    const int tid = threadIdx.x;
    const float px = pos[i*3+0], py = pos[i*3+1], pz = pos[i*3+2];

    // ---- Phase 1: distances to all 1024 points (non-fused fp32, = np's key) ----
    #pragma unroll
    for (int u = 0; u < 4; u++) {
        int j = tid + 256 * u;
        float dx = __fsub_rn(px, pos[j*3+0]);
        float dy = __fsub_rn(py, pos[j*3+1]);
        float dz = __fsub_rn(pz, pos[j*3+2]);
        float s  = __fadd_rn(__fadd_rn(__fmul_rn(dx,dx), __fmul_rn(dy,dy)), __fmul_rn(dz,dz));
        s_dist[j] = __fsqrt_rn(s);
    }
    __syncthreads();

    // ---- Phase 2: wave 0 selects 16 NN; wave 1 computes q = x_i @ Wq ----
    if (tid < 64) {
        int lane = tid;
        float dist[16];
        #pragma unroll
        for (int r = 0; r < 16; r++) dist[r] = s_dist[lane + 64 * r];

        for (int sel = 0; sel < KNN; sel++) {
            float mv = dist[0]; int mr = 0;
            #pragma unroll
            for (int r = 1; r < 16; r++) {
                if (dist[r] < mv) { mv = dist[r]; mr = r; }
            }
            int mj = lane + 64 * mr;
            #pragma unroll
            for (int off = 32; off > 0; off >>= 1) {
                float ov = __shfl_xor(mv, off);
                int   oj = __shfl_xor(mj, off);
                if (ov < mv || (ov == mv && oj < mj)) { mv = ov; mj = oj; }
            }
            if (lane == 0) s_idx[sel] = mj;
            #pragma unroll
            for (int r = 0; r < 16; r++) {
                if (lane + 64 * r == mj) dist[r] = 3.0e38f;
            }
        }
    } else if (tid < 128) {
        int d = tid - 64;
        const float4* xr = (const float4*)(x + i * DIMD);
        float aq = 0.f;
        #pragma unroll
        for (int cb = 0; cb < DIMD / 4; cb++) {
            float4 xv = xr[cb];
            const float* wq = Wq + (cb*4) * DIMD + d;
            aq = fmaf(xv.x, wq[0*DIMD], aq); aq = fmaf(xv.y, wq[1*DIMD], aq);
            aq = fmaf(xv.z, wq[2*DIMD], aq); aq = fmaf(xv.w, wq[3*DIMD], aq);
        }
        s_q[d] = aq;
    }
    __syncthreads();

    // ---- Phase 3: stage the 16 neighbor x rows into LDS ----
    #pragma unroll
    for (int u = 0; u < 4; u++) {
        int t = tid + 256 * u;           // 0..1023
        int kk = t >> 6, c = t & 63;
        s_xn[kk][c] = x[s_idx[kk] * DIMD + c];
    }
    __syncthreads();

    // ---- Step A: emb1 = relu(rel_pos @ P1 + pb1)   [16 x 64] ----
    {
        int m = tid & 63, w = tid >> 6;
        #pragma unroll
        for (int u = 0; u < 4; u++) {
            int kk = w + 4 * u;
            int j = s_idx[kk];
            float dx = px - pos[j*3+0];
            float dy = py - pos[j*3+1];
            float dz = pz - pos[j*3+2];
            float a = pb1[m];
            a = fmaf(dx, P1[0*EMBH+m], a);
            a = fmaf(dy, P1[1*EMBH+m], a);
            a = fmaf(dz, P1[2*EMBH+m], a);
            s_embsim[kk][m] = fmaxf(a, 0.0f);
        }
    }
    __syncthreads();

    // ---- Step B: k_n, v_n recomputed; rpe = emb1@P2+pb2; h = q - k_n + rpe; vg = v_n + rpe ----
    {
        int d = tid & 63, w = tid >> 6;
        float acck[4] = {0.f,0.f,0.f,0.f}, accv[4] = {0.f,0.f,0.f,0.f};
        float rpe[4];
        float pb = pb2[d];
        #pragma unroll
        for (int u = 0; u < 4; u++) rpe[u] = pb;

        #pragma unroll
        for (int cb = 0; cb < DIMD / 4; cb++) {
            const float* wk = Wk + (cb*4) * DIMD + d;
            const float* wv = Wv + (cb*4) * DIMD + d;
            float wk0 = wk[0*DIMD], wk1 = wk[1*DIMD], wk2 = wk[2*DIMD], wk3 = wk[3*DIMD];
            float wv0 = wv[0*DIMD], wv1 = wv[1*DIMD], wv2 = wv[2*DIMD], wv3 = wv[3*DIMD];
            #pragma unroll
            for (int u = 0; u < 4; u++) {
                float4 xv = ((const float4*)(&s_xn[w + 4*u][0]))[cb];   // broadcast
                acck[u] = fmaf(xv.x, wk0, acck[u]); acck[u] = fmaf(xv.y, wk1, acck[u]);
                acck[u] = fmaf(xv.z, wk2, acck[u]); acck[u] = fmaf(xv.w, wk3, acck[u]);
                accv[u] = fmaf(xv.x, wv0, accv[u]); accv[u] = fmaf(xv.y, wv1, accv[u]);
                accv[u] = fmaf(xv.z, wv2, accv[u]); accv[u] = fmaf(xv.w, wv3, accv[u]);
            }
        }
        #pragma unroll
        for (int mb = 0; mb < EMBH / 4; mb++) {
            const float* p2 = P2 + (mb*4) * DIMD + d;
            float p0 = p2[0*DIMD], p1 = p2[1*DIMD], p2v = p2[2*DIMD], p3 = p2[3*DIMD];
            #pragma unroll
            for (int u = 0; u < 4; u++) {
                float4 e = ((const float4*)(&s_embsim[w + 4*u][0]))[mb];  // broadcast
                rpe[u] = fmaf(e.x, p0, rpe[u]); rpe[u] = fmaf(e.y, p1, rpe[u]);
                rpe[u] = fmaf(e.z, p2v, rpe[u]); rpe[u] = fmaf(e.w, p3, rpe[u]);
            }
        }
        float qd = s_q[d];
        #pragma unroll
        for (int u = 0; u < 4; u++) {
            int kk = w + 4 * u;
            s_h[kk][d]  = qd - acck[u] + rpe[u];
            s_vg[kk][d] = accv[u] + rpe[u];
        }
    }
    __syncthreads();

    // ---- Step C: hidden = relu(h @ A1 + ab1)   [16 x 256], thread owns column tid ----
    {
        float acc[KNN];
        float bias = ab1[tid];
        #pragma unroll
        for (int s = 0; s < KNN; s++) acc[s] = bias;
        #pragma unroll
        for (int cb = 0; cb < DIMD / 4; cb++) {
            float a1c[4];
            #pragma unroll
            for (int cc = 0; cc < 4; cc++) a1c[cc] = A1[(cb*4+cc) * HID + tid];
            #pragma unroll
            for (int s = 0; s < KNN; s++) {
                float4 h4 = ((const float4*)(&s_h[s][0]))[cb];   // broadcast
                acc[s] = fmaf(h4.x, a1c[0], acc[s]);
                acc[s] = fmaf(h4.y, a1c[1], acc[s]);
                acc[s] = fmaf(h4.z, a1c[2], acc[s]);
                acc[s] = fmaf(h4.w, a1c[3], acc[s]);
            }
        }
        #pragma unroll
        for (int s = 0; s < KNN; s++) s_hidden[s][tid] = fmaxf(acc[s], 0.0f);
    }
    __syncthreads();

    // ---- Step D: sim = hidden @ A2 + ab2   [16 x 64] ----
    {
        int d = tid & 63;
        int kk0 = tid >> 6;
        float acc[4];
        float bias = ab2[d];
        #pragma unroll
        for (int u = 0; u < 4; u++) acc[u] = bias;
        #pragma unroll
        for (int mb = 0; mb < HID / 4; mb++) {
            float a2c[4];
            #pragma unroll
            for (int mm = 0; mm < 4; mm++) a2c[mm] = A2[(mb*4+mm) * DIMD + d];
            #pragma unroll
            for (int u = 0; u < 4; u++) {
                float4 h4 = ((const float4*)(&s_hidden[kk0 + 4*u][0]))[mb];  // broadcast
                acc[u] = fmaf(h4.x, a2c[0], acc[u]);
                acc[u] = fmaf(h4.y, a2c[1], acc[u]);
                acc[u] = fmaf(h4.z, a2c[2], acc[u]);
                acc[u] = fmaf(h4.w, a2c[3], acc[u]);
            }
        }
        __syncthreads();   // emb1 region dead; safe to overwrite with sim
        #pragma unroll
        for (int u = 0; u < 4; u++) s_embsim[kk0 + 4*u][d] = acc[u];
    }
    __syncthreads();

    // ---- Step E: softmax over neighbors per dim, weighted sum of vg ----
    if (tid < DIMD) {
        int d = tid;
        float mx = -3.0e38f;
        #pragma unroll
        for (int kk = 0; kk < KNN; kk++) mx = fmaxf(mx, s_embsim[kk][d]);
        float den = 0.0f, num = 0.0f;
        #pragma unroll
        for (int kk = 0; kk < KNN; kk++) {
            float e = expf(s_embsim[kk][d] - mx);
            den += e;
            num = fmaf(e, s_vg[kk][d], num);
        }
        out[i * DIMD + d] = num / den;
    }
}

extern "C" void kernel_launch(void* const* d_in, const int* in_sizes, int n_in,
                              void* d_out, int out_size, void* d_ws, size_t ws_size,
                              hipStream_t stream) {
    const float* x   = (const float*)d_in[0];
    const float* pos = (const float*)d_in[1];
    const float* Wq  = (const float*)d_in[2];
    const float* Wk  = (const float*)d_in[3];
    const float* Wv  = (const float*)d_in[4];
    const float* P1  = (const float*)d_in[5];
    const float* pb1 = (const float*)d_in[6];
    const float* P2  = (const float*)d_in[7];
    const float* pb2 = (const float*)d_in[8];
    const float* A1  = (const float*)d_in[9];
    const float* ab1 = (const float*)d_in[10];
    const float* A2  = (const float*)d_in[11];
    const float* ab2 = (const float*)d_in[12];
    float* out = (float*)d_out;

    ptl_fused<<<NPTS, 256, 0, stream>>>(x, pos, Wq, Wk, Wv,
                                        P1, pb1, P2, pb2, A1, ab1, A2, ab2, out);
}

// Round 6
// 106.922 us; speedup vs baseline: 1.1338x; 1.1126x over previous
//
#include <hip/hip_runtime.h>

#define NPTS 1024
#define DIMD 64
#define KNN  16
#define HID  256
#define EMBH 64

typedef short short8 __attribute__((ext_vector_type(8)));
typedef float f32x4  __attribute__((ext_vector_type(4)));

__device__ __forceinline__ short f2bf(float x) {            // RNE fp32->bf16
    unsigned u = __float_as_uint(x);
    unsigned r = (u + 0x7fffu + ((u >> 16) & 1u)) >> 16;
    return (short)r;
}
__device__ __forceinline__ float bf2f(short s) {
    return __uint_as_float(((unsigned)(unsigned short)s) << 16);
}

// fragment offset (in shorts) for B-operand of mfma_f32_16x16x32_bf16:
// B[k][n]: lane = ((k>>3)&3)<<4 | (n&15), j = k&7, frag = (n>>4)*(K/32) + (k>>5)
__device__ __host__ __forceinline__ int frag_off(int K, int k, int n) {
    int T = n >> 4, c = k >> 5, q = (k >> 3) & 3, j = k & 7;
    int lane = (q << 4) | (n & 15);
    return ((T * (K >> 5) + c) * 64 + lane) * 8 + j;
}

// ws layout (shorts):
#define A1HI 0
#define A1LO 16384
#define A2HI 32768
#define A2LO 49152
#define WKHI 65536
#define WKLO 69632
#define WVHI 73728
#define WVLO 77824
#define P2HI 81920
#define P2LO 86016
#define WS_SHORTS 90112

// ---------- prep: convert weights to B-fragment bf16 hi/lo layout ----------
__global__ __launch_bounds__(256) void prep_weights(
    const float* __restrict__ A1, const float* __restrict__ A2,
    const float* __restrict__ Wk, const float* __restrict__ Wv,
    const float* __restrict__ P2, short* __restrict__ ws)
{
    int e = blockIdx.x * 256 + threadIdx.x;   // 0..45055
    float v; int hi_base, lo_base, off;
    if (e < 16384)      { int k = e >> 8, n = e & 255;               v = A1[e];
                          hi_base = A1HI; lo_base = A1LO; off = frag_off(64,  k, n); }
    else if (e < 32768) { int t = e - 16384; int k = t >> 6, n = t & 63; v = A2[t];
                          hi_base = A2HI; lo_base = A2LO; off = frag_off(256, k, n); }
    else if (e < 36864) { int t = e - 32768; int k = t >> 6, n = t & 63; v = Wk[t];
                          hi_base = WKHI; lo_base = WKLO; off = frag_off(64,  k, n); }
    else if (e < 40960) { int t = e - 36864; int k = t >> 6, n = t & 63; v = Wv[t];
                          hi_base = WVHI; lo_base = WVLO; off = frag_off(64,  k, n); }
    else if (e < 45056) { int t = e - 40960; int k = t >> 6, n = t & 63; v = P2[t];
                          hi_base = P2HI; lo_base = P2LO; off = frag_off(64,  k, n); }
    else return;
    short h = f2bf(v);
    short l = f2bf(v - bf2f(h));
    ws[hi_base + off] = h;
    ws[lo_base + off] = l;
}

// ---------- main fused kernel: one block (256 thr) per point ----------
__global__ __launch_bounds__(256, 4) void ptl_fused(
    const float* __restrict__ x,  const float* __restrict__ pos,
    const float* __restrict__ Wq,
    const float* __restrict__ P1, const float* __restrict__ pb1,
    const float* __restrict__ pb2,
    const float* __restrict__ ab1, const float* __restrict__ ab2,
    const short* __restrict__ ws,
    float* __restrict__ out)
{
    __shared__ __align__(16) float s_big[16 * 260];   // dist[1024] | hidden[16][260]
    __shared__ __align__(16) float s_es[16 * 68];     // emb1 | sim
    __shared__ __align__(16) float s_xn[16 * 68];
    __shared__ __align__(16) float s_h[16 * 68];
    __shared__ __align__(16) float s_vg[16 * 68];
    __shared__ float s_q[DIMD];
    __shared__ int s_idx[KNN];

    const int i   = blockIdx.x;
    const int tid = threadIdx.x;
    const int lane = tid & 63;
    const int w    = tid >> 6;        // wave id 0..3
    const int q4   = lane >> 4;       // quad
    const int col  = lane & 15;

    const float px = pos[i*3+0], py = pos[i*3+1], pz = pos[i*3+2];

    // ---- Phase 1: distances (non-fused fp32 = np's compare key) ----
    #pragma unroll
    for (int u = 0; u < 4; u++) {
        int j = tid + 256 * u;
        float dx = __fsub_rn(px, pos[j*3+0]);
        float dy = __fsub_rn(py, pos[j*3+1]);
        float dz = __fsub_rn(pz, pos[j*3+2]);
        float s  = __fadd_rn(__fadd_rn(__fmul_rn(dx,dx), __fmul_rn(dy,dy)), __fmul_rn(dz,dz));
        s_big[j] = __fsqrt_rn(s);
    }
    __syncthreads();

    // ---- Phase 2: wave 0 selects 16 NN; wave 1 computes q = x_i @ Wq ----
    if (tid < 64) {
        float dist[16];
        #pragma unroll
        for (int r = 0; r < 16; r++) dist[r] = s_big[lane + 64 * r];
        for (int sel = 0; sel < KNN; sel++) {
            float mv = dist[0]; int mr = 0;
            #pragma unroll
            for (int r = 1; r < 16; r++) if (dist[r] < mv) { mv = dist[r]; mr = r; }
            int mj = lane + 64 * mr;
            #pragma unroll
            for (int off = 32; off > 0; off >>= 1) {
                float ov = __shfl_xor(mv, off);
                int   oj = __shfl_xor(mj, off);
                if (ov < mv || (ov == mv && oj < mj)) { mv = ov; mj = oj; }
            }
            if (lane == 0) s_idx[sel] = mj;
            #pragma unroll
            for (int r = 0; r < 16; r++) if (lane + 64 * r == mj) dist[r] = 3.0e38f;
        }
    } else if (tid < 128) {
        int d = tid - 64;
        const float4* xr = (const float4*)(x + i * DIMD);
        float aq = 0.f;
        #pragma unroll
        for (int cb = 0; cb < DIMD / 4; cb++) {
            float4 xv = xr[cb];
            const float* wq = Wq + (cb*4) * DIMD + d;
            aq = fmaf(xv.x, wq[0*DIMD], aq); aq = fmaf(xv.y, wq[1*DIMD], aq);
            aq = fmaf(xv.z, wq[2*DIMD], aq); aq = fmaf(xv.w, wq[3*DIMD], aq);
        }
        s_q[d] = aq;
    }
    __syncthreads();

    // ---- Phase 3: stage neighbor x rows + emb1 = relu(rel_pos@P1+pb1) ----
    #pragma unroll
    for (int u = 0; u < 4; u++) {
        int t = tid + 256 * u;          // 0..1023
        int kk = t >> 6, c = t & 63;
        s_xn[kk * 68 + c] = x[s_idx[kk] * DIMD + c];
        int j = s_idx[kk];
        float dx = px - pos[j*3+0];
        float dy = py - pos[j*3+1];
        float dz = pz - pos[j*3+2];
        float a = pb1[c];
        a = fmaf(dx, P1[0*EMBH+c], a);
        a = fmaf(dy, P1[1*EMBH+c], a);
        a = fmaf(dz, P1[2*EMBH+c], a);
        s_es[kk * 68 + c] = fmaxf(a, 0.0f);
    }
    __syncthreads();

    const short8* wsv = (const short8*)ws;

    // helper: build hi/lo A-frags from padded LDS row
    auto build_afrag = [&](const float* row, int kbase, short8& hi, short8& lo) {
        #pragma unroll
        for (int j = 0; j < 8; j++) {
            float xv = row[kbase + j];
            short h = f2bf(xv);
            hi[j] = h;
            lo[j] = f2bf(xv - bf2f(h));
        }
    };
    auto bfrag = [&](int short_base, int f) -> short8 {
        return wsv[(short_base >> 3) + f * 64 + lane];
    };

    // ---- Group 1 MFMA: kn = xn@Wk, vn = xn@Wv, rpe = emb1@P2 (each 16x64, K=64) ----
    {
        short8 xhi[2], xlo[2], ehi[2], elo[2];
        #pragma unroll
        for (int c = 0; c < 2; c++) {
            build_afrag(s_xn + (lane & 15) * 68, 32*c + q4*8, xhi[c], xlo[c]);
            build_afrag(s_es + (lane & 15) * 68, 32*c + q4*8, ehi[c], elo[c]);
        }
        f32x4 acck = {0,0,0,0}, accv = {0,0,0,0}, accr = {0,0,0,0};
        #pragma unroll
        for (int c = 0; c < 2; c++) {
            int f = w * 2 + c;
            short8 bkh = bfrag(WKHI, f), bkl = bfrag(WKLO, f);
            short8 bvh = bfrag(WVHI, f), bvl = bfrag(WVLO, f);
            short8 bph = bfrag(P2HI, f), bpl = bfrag(P2LO, f);
            acck = __builtin_amdgcn_mfma_f32_16x16x32_bf16(xhi[c], bkh, acck, 0,0,0);
            acck = __builtin_amdgcn_mfma_f32_16x16x32_bf16(xhi[c], bkl, acck, 0,0,0);
            acck = __builtin_amdgcn_mfma_f32_16x16x32_bf16(xlo[c], bkh, acck, 0,0,0);
            accv = __builtin_amdgcn_mfma_f32_16x16x32_bf16(xhi[c], bvh, accv, 0,0,0);
            accv = __builtin_amdgcn_mfma_f32_16x16x32_bf16(xhi[c], bvl, accv, 0,0,0);
            accv = __builtin_amdgcn_mfma_f32_16x16x32_bf16(xlo[c], bvh, accv, 0,0,0);
            accr = __builtin_amdgcn_mfma_f32_16x16x32_bf16(ehi[c], bph, accr, 0,0,0);
            accr = __builtin_amdgcn_mfma_f32_16x16x32_bf16(ehi[c], bpl, accr, 0,0,0);
            accr = __builtin_amdgcn_mfma_f32_16x16x32_bf16(elo[c], bph, accr, 0,0,0);
        }
        int d = w * 16 + col;
        float qd = s_q[d], pb = pb2[d];
        #pragma unroll
        for (int r = 0; r < 4; r++) {
            int s = q4 * 4 + r;
            float rpe = accr[r] + pb;
            s_h[s * 68 + d]  = qd - acck[r] + rpe;
            s_vg[s * 68 + d] = accv[r] + rpe;
        }
    }
    __syncthreads();

    // ---- Step C MFMA: hidden = relu(h @ A1 + ab1), 16x256, K=64 ----
    {
        short8 hhi[2], hlo[2];
        #pragma unroll
        for (int c = 0; c < 2; c++)
            build_afrag(s_h + (lane & 15) * 68, 32*c + q4*8, hhi[c], hlo[c]);
        #pragma unroll
        for (int t = 0; t < 4; t++) {
            int T = w * 4 + t;
            f32x4 acc = {0,0,0,0};
            #pragma unroll
            for (int c = 0; c < 2; c++) {
                int f = T * 2 + c;
                short8 bh = bfrag(A1HI, f), bl = bfrag(A1LO, f);
                acc = __builtin_amdgcn_mfma_f32_16x16x32_bf16(hhi[c], bh, acc, 0,0,0);
                acc = __builtin_amdgcn_mfma_f32_16x16x32_bf16(hhi[c], bl, acc, 0,0,0);
                acc = __builtin_amdgcn_mfma_f32_16x16x32_bf16(hlo[c], bh, acc, 0,0,0);
            }
            int n = T * 16 + col;
            float bias = ab1[n];
            #pragma unroll
            for (int r = 0; r < 4; r++)
                s_big[(q4 * 4 + r) * 260 + n] = fmaxf(acc[r] + bias, 0.0f);
        }
    }
    __syncthreads();

    // ---- Step D MFMA: sim = hidden @ A2 + ab2, 16x64, K=256 ----
    {
        f32x4 acc = {0,0,0,0};
        #pragma unroll
        for (int c = 0; c < 8; c++) {
            short8 ahi, alo;
            build_afrag(s_big + (lane & 15) * 260, 32*c + q4*8, ahi, alo);
            int f = w * 8 + c;
            short8 bh = bfrag(A2HI, f), bl = bfrag(A2LO, f);
            acc = __builtin_amdgcn_mfma_f32_16x16x32_bf16(ahi, bh, acc, 0,0,0);
            acc = __builtin_amdgcn_mfma_f32_16x16x32_bf16(ahi, bl, acc, 0,0,0);
            acc = __builtin_amdgcn_mfma_f32_16x16x32_bf16(alo, bh, acc, 0,0,0);
        }
        int n = w * 16 + col;
        float bias = ab2[n];
        #pragma unroll
        for (int r = 0; r < 4; r++)
            s_es[(q4 * 4 + r) * 68 + n] = acc[r] + bias;   // sim overwrites emb1
    }
    __syncthreads();

    // ---- Step E: softmax over neighbors per dim, weighted sum of vg ----
    if (tid < DIMD) {
        int d = tid;
        float mx = -3.0e38f;
        #pragma unroll
        for (int kk = 0; kk < KNN; kk++) mx = fmaxf(mx, s_es[kk * 68 + d]);
        float den = 0.0f, num = 0.0f;
        #pragma unroll
        for (int kk = 0; kk < KNN; kk++) {
            float e = expf(s_es[kk * 68 + d] - mx);
            den += e;
            num = fmaf(e, s_vg[kk * 68 + d], num);
        }
        out[i * DIMD + d] = num / den;
    }
}

extern "C" void kernel_launch(void* const* d_in, const int* in_sizes, int n_in,
                              void* d_out, int out_size, void* d_ws, size_t ws_size,
                              hipStream_t stream) {
    const float* x   = (const float*)d_in[0];
    const float* pos = (const float*)d_in[1];
    const float* Wq  = (const float*)d_in[2];
    const float* Wk  = (const float*)d_in[3];
    const float* Wv  = (const float*)d_in[4];
    const float* P1  = (const float*)d_in[5];
    const float* pb1 = (const float*)d_in[6];
    const float* P2  = (const float*)d_in[7];
    const float* pb2 = (const float*)d_in[8];
    const float* A1  = (const float*)d_in[9];
    const float* ab1 = (const float*)d_in[10];
    const float* A2  = (const float*)d_in[11];
    const float* ab2 = (const float*)d_in[12];
    float* out = (float*)d_out;
    short* ws  = (short*)d_ws;

    prep_weights<<<(45056 + 255) / 256, 256, 0, stream>>>(A1, A2, Wk, Wv, P2, ws);
    ptl_fused<<<NPTS, 256, 0, stream>>>(x, pos, Wq, P1, pb1, pb2, ab1, ab2, ws, out);
}